// Round 7
// baseline (566.374 us; speedup 1.0000x reference)
//
#include <hip/hip_runtime.h>

typedef _Float16 half8 __attribute__((ext_vector_type(8)));
typedef float floatx4 __attribute__((ext_vector_type(4)));

#define DDIM 64
#define LN_EPS 1e-5f
#define SHIFT 20.0f

#define RB 128        // query rows per block
#define ROWB 144      // LDS row stride in bytes (144: 16B-aligned, 2-way bank alias free)
#define CK0 128       // pass0 chunk rows
#define CK1 64        // pass1 chunk rows
#define PLB0 (CK0 * ROWB)  // 18432 B per plane (pass0)
#define PLB1 (CK1 * ROWB)  // 9216 B per plane (pass1)
#define PSTR 68       // Pbuf row stride in floats (272 B)

__device__ inline float wave_sum(float v) {
#pragma unroll
  for (int m = 1; m < 64; m <<= 1) v += __shfl_xor(v, m, 64);
  return v;
}

// LayerNorm both tables, emit f16 hi/lo split planes. One wave per row.
__global__ __launch_bounds__(256) void ln_kernel(
    const float* __restrict__ Eo, const float* __restrict__ Ed,
    const float* __restrict__ go, const float* __restrict__ bo,
    const float* __restrict__ gd, const float* __restrict__ bd,
    _Float16* __restrict__ Co_hi, _Float16* __restrict__ Co_lo,
    _Float16* __restrict__ Cd_hi, _Float16* __restrict__ Cd_lo, int N) {
  int row = blockIdx.x * 4 + (threadIdx.x >> 6);
  if (row >= N) return;
  int lane = threadIdx.x & 63;
  size_t idx = (size_t)row * DDIM + lane;
  {
    float x = Eo[idx];
    float m = wave_sum(x) * (1.0f / DDIM);
    float d = x - m;
    float var = wave_sum(d * d) * (1.0f / DDIM);
    float y = d * rsqrtf(var + LN_EPS) * go[lane] + bo[lane];
    _Float16 hi = (_Float16)y;
    Co_hi[idx] = hi;
    Co_lo[idx] = (_Float16)(y - (float)hi);
  }
  {
    float x = Ed[idx];
    float m = wave_sum(x) * (1.0f / DDIM);
    float d = x - m;
    float var = wave_sum(d * d) * (1.0f / DDIM);
    float y = d * rsqrtf(var + LN_EPS) * gd[lane] + bd[lane];
    _Float16 hi = (_Float16)y;
    Cd_hi[idx] = hi;
    Cd_lo[idx] = (_Float16)(y - (float)hi);
  }
}

// PASS 0: accumulate sum of exp(score - SHIFT) per row (atomics).
// CK0=128 (half the barrier rounds of CK=64) + T14 async-stage: chunk k+1's
// global loads are issued into registers BEFORE chunk k's compute, so the
// L2/L3 load latency hides under MFMA+exp instead of serializing per chunk.
// Scores via split-f16 MFMA: s = qh*ch + qh*cl + ql*ch (ql*cl dropped).
__global__ __launch_bounds__(256, 3) void pass0_kernel(
    const _Float16* __restrict__ Co_hi, const _Float16* __restrict__ Co_lo,
    const _Float16* __restrict__ Cd_hi, const _Float16* __restrict__ Cd_lo,
    const int* __restrict__ ids, float* __restrict__ sums,
    int N, int B, int nc_total) {
  // [2 planes][128 rows][144 B] = 36864 B -> 3 blocks/CU.
  __shared__ __attribute__((aligned(16))) char Sbuf[2 * PLB0];

  const int t = threadIdx.x;
  const int mat = blockIdx.z;
  const int mbase = blockIdx.y * RB;
  const _Float16* Qsrc_h = (mat == 0) ? Co_hi : Cd_hi;
  const _Float16* Qsrc_l = (mat == 0) ? Co_lo : Cd_lo;
  const _Float16* Csrc_h = (mat == 0) ? Cd_hi : Co_hi;
  const _Float16* Csrc_l = (mat == 0) ? Cd_lo : Co_lo;

  const int lane = t & 63;
  const int wv = t >> 6;
  const int l15 = lane & 15;
  const int quad = lane >> 4;

  // ---- Stage Q-hi -> Sbuf[0], Q-lo -> Sbuf[PLB0] (both at once), read A frags.
#pragma unroll
  for (int j = 0; j < 4; ++j) {
    int f = (j * 256 + t) * 16;  // [0,16384): byte offset in [128][128B] image
    int r = f >> 7;
    int off = f & 127;
    int id = ids[mbase + r];
    *(uint4*)(Sbuf + r * ROWB + off) =
        *(const uint4*)((const char*)Qsrc_h + (size_t)id * 128 + off);
    *(uint4*)(Sbuf + PLB0 + r * ROWB + off) =
        *(const uint4*)((const char*)Qsrc_l + (size_t)id * 128 + off);
  }
  __syncthreads();
  half8 Ah[2][2], Al[2][2];
#pragma unroll
  for (int mt = 0; mt < 2; ++mt) {
    int r = wv * 32 + mt * 16 + l15;
    const char* qh = Sbuf + r * ROWB + quad * 16;
    Ah[mt][0] = *(const half8*)qh;
    Ah[mt][1] = *(const half8*)(qh + 64);
    Al[mt][0] = *(const half8*)(qh + PLB0);
    Al[mt][1] = *(const half8*)(qh + PLB0 + 64);
  }
  __syncthreads();  // Q reads done; Sbuf free for C chunks

  float sumacc[2][4];
#pragma unroll
  for (int mt = 0; mt < 2; ++mt)
#pragma unroll
    for (int r2 = 0; r2 < 4; ++r2) sumacc[mt][r2] = 0.0f;

  const int bx = blockIdx.x;
  const int gxd = gridDim.x;
  int nck = (nc_total - 1 - bx) / gxd + 1;

  // Register staging: 8 uint4/thread = one CK0 chunk (both planes, 32 KB/block)
  uint4 stg[8];
  auto load_regs = [&](int k) {
    int nbase = (bx + k * gxd) * CK0;
#pragma unroll
    for (int u = 0; u < 8; ++u) {
      int f = (u * 256 + t) * 16;  // [0,32768)
      int p = f >> 14;             // plane
      int fp = f & 16383;
      int r = fp >> 7;
      int off = fp & 127;
      int gr = nbase + r;
      if (gr > N - 1) gr = N - 1;  // clamp; masked at use
      const char* src = (p == 0) ? (const char*)Csrc_h : (const char*)Csrc_l;
      stg[u] = *(const uint4*)(src + (size_t)gr * 128 + off);
    }
  };

  load_regs(0);
  for (int k = 0; k < nck; ++k) {
    // write staged regs -> Sbuf (prev compute's reads done: barrier at loop end)
#pragma unroll
    for (int u = 0; u < 8; ++u) {
      int f = (u * 256 + t) * 16;
      int p = f >> 14;
      int fp = f & 16383;
      int r = fp >> 7;
      int off = fp & 127;
      *(uint4*)(Sbuf + p * PLB0 + r * ROWB + off) = stg[u];
    }
    __syncthreads();
    if (k + 1 < nck) load_regs(k + 1);  // latency hides under compute below

    int nbase = (bx + k * gxd) * CK0;
#pragma unroll
    for (int nt = 0; nt < 8; ++nt) {
      int cr = nt * 16 + l15;
      const char* bh = Sbuf + cr * ROWB + quad * 16;
      const char* bl = bh + PLB0;
      half8 Bh0 = *(const half8*)bh;
      half8 Bh1 = *(const half8*)(bh + 64);
      half8 Bl0 = *(const half8*)bl;
      half8 Bl1 = *(const half8*)(bl + 64);
      int col = nbase + nt * 16 + l15;
      bool valid = col < N;
#pragma unroll
      for (int mt = 0; mt < 2; ++mt) {
        floatx4 acc = {0.0f, 0.0f, 0.0f, 0.0f};
        acc = __builtin_amdgcn_mfma_f32_16x16x32_f16(Ah[mt][0], Bh0, acc, 0, 0, 0);
        acc = __builtin_amdgcn_mfma_f32_16x16x32_f16(Ah[mt][1], Bh1, acc, 0, 0, 0);
        acc = __builtin_amdgcn_mfma_f32_16x16x32_f16(Ah[mt][0], Bl0, acc, 0, 0, 0);
        acc = __builtin_amdgcn_mfma_f32_16x16x32_f16(Ah[mt][1], Bl1, acc, 0, 0, 0);
        acc = __builtin_amdgcn_mfma_f32_16x16x32_f16(Al[mt][0], Bh0, acc, 0, 0, 0);
        acc = __builtin_amdgcn_mfma_f32_16x16x32_f16(Al[mt][1], Bh1, acc, 0, 0, 0);
#pragma unroll
        for (int r2 = 0; r2 < 4; ++r2) {
          float p = __expf(acc[r2] - SHIFT);
          sumacc[mt][r2] += valid ? p : 0.0f;
        }
      }
    }
    __syncthreads();  // Sbuf reads done before next ds_write
  }

  // per-row partial sums -> atomics
#pragma unroll
  for (int mt = 0; mt < 2; ++mt)
#pragma unroll
    for (int r2 = 0; r2 < 4; ++r2) {
      float v = sumacc[mt][r2];
      v += __shfl_xor(v, 1, 64);
      v += __shfl_xor(v, 2, 64);
      v += __shfl_xor(v, 4, 64);
      v += __shfl_xor(v, 8, 64);
      if (l15 == 0) {
        int rl = wv * 32 + mt * 16 + quad * 4 + r2;
        atomicAdd(&sums[(size_t)mat * B + mbase + rl], v);
      }
    }
}

// PASS 1: write exp(score - SHIFT) * inv_sum via LDS transpose tile (Pbuf)
// flushed as 256 B contiguous 128B-aligned per-row segments (verified win:
// avoids L2 read-modify-write on scattered 64B stores). CK1=64 so Pbuf fits;
// T14 async-stage as in pass 0. Q-lo staged through Pbuf's storage.
__global__ __launch_bounds__(256, 3) void pass1_kernel(
    const _Float16* __restrict__ Co_hi, const _Float16* __restrict__ Co_lo,
    const _Float16* __restrict__ Cd_hi, const _Float16* __restrict__ Cd_lo,
    const int* __restrict__ ids, const float* __restrict__ sums,
    float* __restrict__ out, int N, int B, int nc_total) {
  __shared__ __attribute__((aligned(16))) char Sbuf[2 * PLB1];            // 18432
  __shared__ __attribute__((aligned(16))) float Pbuf[RB * PSTR];          // 34816
  __shared__ float inv_lds[RB];                                           // 512
  // total 53760 B -> 3 blocks/CU

  const int t = threadIdx.x;
  const int mat = blockIdx.z;
  const int mbase = blockIdx.y * RB;
  const _Float16* Qsrc_h = (mat == 0) ? Co_hi : Cd_hi;
  const _Float16* Qsrc_l = (mat == 0) ? Co_lo : Cd_lo;
  const _Float16* Csrc_h = (mat == 0) ? Cd_hi : Co_hi;
  const _Float16* Csrc_l = (mat == 0) ? Cd_lo : Co_lo;

  const int lane = t & 63;
  const int wv = t >> 6;
  const int l15 = lane & 15;
  const int quad = lane >> 4;

  if (t < RB) inv_lds[t] = 1.0f / sums[(size_t)mat * B + mbase + t];

  // ---- Stage Q-hi -> Sbuf, Q-lo -> Pbuf storage (both at once).
  char* Qlo_area = (char*)Pbuf;
#pragma unroll
  for (int j = 0; j < 4; ++j) {
    int f = (j * 256 + t) * 16;
    int r = f >> 7;
    int off = f & 127;
    int id = ids[mbase + r];
    *(uint4*)(Sbuf + r * ROWB + off) =
        *(const uint4*)((const char*)Qsrc_h + (size_t)id * 128 + off);
    *(uint4*)(Qlo_area + r * ROWB + off) =
        *(const uint4*)((const char*)Qsrc_l + (size_t)id * 128 + off);
  }
  __syncthreads();
  half8 Ah[2][2], Al[2][2];
#pragma unroll
  for (int mt = 0; mt < 2; ++mt) {
    int r = wv * 32 + mt * 16 + l15;
    const char* qh = Sbuf + r * ROWB + quad * 16;
    const char* ql = Qlo_area + r * ROWB + quad * 16;
    Ah[mt][0] = *(const half8*)qh;
    Ah[mt][1] = *(const half8*)(qh + 64);
    Al[mt][0] = *(const half8*)ql;
    Al[mt][1] = *(const half8*)(ql + 64);
  }
  float invr[2][4];
#pragma unroll
  for (int mt = 0; mt < 2; ++mt)
#pragma unroll
    for (int r2 = 0; r2 < 4; ++r2)
      invr[mt][r2] = inv_lds[wv * 32 + mt * 16 + quad * 4 + r2];
  __syncthreads();  // Q reads done; Sbuf + Pbuf free

  const int bx = blockIdx.x;
  const int gxd = gridDim.x;
  int nck = (nc_total - 1 - bx) / gxd + 1;
  float* orow = out + (size_t)mat * B * N + (size_t)mbase * N;

  uint4 stg[4];
  auto load_regs = [&](int k) {
    int nbase = (bx + k * gxd) * CK1;
#pragma unroll
    for (int u = 0; u < 4; ++u) {
      int f = (u * 256 + t) * 16;  // [0,16384)
      int p = f >> 13;             // plane (per-plane image 8192 B)
      int fp = f & 8191;
      int r = fp >> 7;
      int off = fp & 127;
      int gr = nbase + r;
      if (gr > N - 1) gr = N - 1;
      const char* src = (p == 0) ? (const char*)Csrc_h : (const char*)Csrc_l;
      stg[u] = *(const uint4*)(src + (size_t)gr * 128 + off);
    }
  };

  load_regs(0);
  for (int k = 0; k < nck; ++k) {
#pragma unroll
    for (int u = 0; u < 4; ++u) {
      int f = (u * 256 + t) * 16;
      int p = f >> 13;
      int fp = f & 8191;
      int r = fp >> 7;
      int off = fp & 127;
      *(uint4*)(Sbuf + p * PLB1 + r * ROWB + off) = stg[u];
    }
    __syncthreads();
    if (k + 1 < nck) load_regs(k + 1);  // latency hides under compute

    int nbase = (bx + k * gxd) * CK1;
#pragma unroll
    for (int nt = 0; nt < 4; ++nt) {
      int cr = nt * 16 + l15;
      const char* bh = Sbuf + cr * ROWB + quad * 16;
      const char* bl = bh + PLB1;
      half8 Bh0 = *(const half8*)bh;
      half8 Bh1 = *(const half8*)(bh + 64);
      half8 Bl0 = *(const half8*)bl;
      half8 Bl1 = *(const half8*)(bl + 64);
#pragma unroll
      for (int mt = 0; mt < 2; ++mt) {
        floatx4 acc = {0.0f, 0.0f, 0.0f, 0.0f};
        acc = __builtin_amdgcn_mfma_f32_16x16x32_f16(Ah[mt][0], Bh0, acc, 0, 0, 0);
        acc = __builtin_amdgcn_mfma_f32_16x16x32_f16(Ah[mt][1], Bh1, acc, 0, 0, 0);
        acc = __builtin_amdgcn_mfma_f32_16x16x32_f16(Ah[mt][0], Bl0, acc, 0, 0, 0);
        acc = __builtin_amdgcn_mfma_f32_16x16x32_f16(Ah[mt][1], Bl1, acc, 0, 0, 0);
        acc = __builtin_amdgcn_mfma_f32_16x16x32_f16(Al[mt][0], Bh0, acc, 0, 0, 0);
        acc = __builtin_amdgcn_mfma_f32_16x16x32_f16(Al[mt][1], Bh1, acc, 0, 0, 0);
#pragma unroll
        for (int r2 = 0; r2 < 4; ++r2) {
          float p = __expf(acc[r2] - SHIFT);
          int rl = wv * 32 + mt * 16 + quad * 4 + r2;
          Pbuf[rl * PSTR + nt * 16 + l15] = p * invr[mt][r2];
        }
      }
    }
    __syncthreads();  // Pbuf complete; Sbuf reads done

    // Flush Pbuf -> out: 128 rows x 64 cols; 16 threads/row, floatx4 each
    // -> 256 B contiguous, 128B-aligned segments. Overlaps next ds_write+loads.
#pragma unroll
    for (int i = 0; i < 8; ++i) {
      int fl = i * 256 + t;
      int row = fl >> 4;
      int c4 = fl & 15;
      int gcol = nbase + c4 * 4;
      if (gcol < N) {
        floatx4 v = *(const floatx4*)&Pbuf[row * PSTR + c4 * 4];
        __builtin_nontemporal_store(v, (floatx4*)(orow + (size_t)row * N + gcol));
      }
    }
    // next iteration's first barrier orders flush's Pbuf reads before the
    // next compute's Pbuf writes.
  }
}

extern "C" void kernel_launch(void* const* d_in, const int* in_sizes, int n_in,
                              void* d_out, int out_size, void* d_ws, size_t ws_size,
                              hipStream_t stream) {
  const int* ids = (const int*)d_in[0];
  const float* Eo = (const float*)d_in[1];
  const float* Ed = (const float*)d_in[2];
  const float* go = (const float*)d_in[3];
  const float* bo = (const float*)d_in[4];
  const float* gd = (const float*)d_in[5];
  const float* bd = (const float*)d_in[6];
  const int B = in_sizes[0];          // 512
  const int N = in_sizes[1] / DDIM;   // 100000
  float* out = (float*)d_out;

  char* ws = (char*)d_ws;
  size_t plane = (size_t)N * DDIM * sizeof(_Float16);  // 12.8 MB
  _Float16* Co_hi = (_Float16*)(ws + 0 * plane);
  _Float16* Co_lo = (_Float16*)(ws + 1 * plane);
  _Float16* Cd_hi = (_Float16*)(ws + 2 * plane);
  _Float16* Cd_lo = (_Float16*)(ws + 3 * plane);
  float* sums = (float*)(ws + 4 * plane);  // 2*B floats

  (void)hipMemsetAsync(sums, 0, (size_t)2 * B * sizeof(float), stream);

  ln_kernel<<<(N + 3) / 4, 256, 0, stream>>>(Eo, Ed, go, bo, gd, bd,
                                             Co_hi, Co_lo, Cd_hi, Cd_lo, N);

  // 96 x-blocks * 4 * 2 = 768 blocks = 3 blocks/CU x 256 CU. Blocks sharing
  // a chunk stream are 96 apart (96 % 8 == 0 -> same XCD -> L2 reuse).
  int nc0 = (N + CK0 - 1) / CK0;  // 782
  int nc1 = (N + CK1 - 1) / CK1;  // 1563
  dim3 sgrid(96, B / RB, 2);
  pass0_kernel<<<sgrid, 256, 0, stream>>>(Co_hi, Co_lo, Cd_hi, Cd_lo, ids,
                                          sums, N, B, nc0);
  pass1_kernel<<<sgrid, 256, 0, stream>>>(Co_hi, Co_lo, Cd_hi, Cd_lo, ids,
                                          sums, out, N, B, nc1);
}